// Round 6
// baseline (539.099 us; speedup 1.0000x reference)
//
#include <hip/hip_runtime.h>
#include <hip/hip_bf16.h>
#include <stdint.h>

#define HFR 128
#define HTO 128
#define LDN 136

typedef short short8 __attribute__((ext_vector_type(8)));   // 8 bf16 = 4 VGPRs
typedef float f32x4  __attribute__((ext_vector_type(4)));   // MFMA C/D
typedef unsigned long long u64;

static __device__ __forceinline__ unsigned short f2bf(float x) {
    __hip_bfloat16 h = __float2bfloat16(x);
    return *reinterpret_cast<unsigned short*>(&h);
}
static __device__ __forceinline__ float bflo(unsigned int x) {
    return __uint_as_float(x << 16);           // low bf16 -> f32
}
static __device__ __forceinline__ float bfhi(unsigned int x) {
    return __uint_as_float(x & 0xffff0000u);   // high bf16 -> f32
}

// ---------------------------------------------------------------------------
// prep: three block ranges.
//   [0, ZB)        : zero cnt[nseg] (int4 stores)
//   [ZB, ZB+CB)    : nodes fp32 -> bf16 (N*128 elems, 8/thread)
//   [ZB+CB, +WB)   : weights fp32 -> bf16 (R*128*128 elems, 8/thread)
// ---------------------------------------------------------------------------
__global__ __launch_bounds__(256)
void prep_kernel(const float* __restrict__ nodes, const float* __restrict__ weights,
                 int* __restrict__ cnt, unsigned short* __restrict__ nb,
                 unsigned short* __restrict__ wb,
                 int nseg, int nfeat, int nw, int ZB, int CB) {
    int b = blockIdx.x;
    if (b < ZB) {
        int i = (b * 256 + threadIdx.x) * 4;
        if (i < nseg) {                       // nseg % 4 == 0
            int4 z = make_int4(0, 0, 0, 0);
            *reinterpret_cast<int4*>(cnt + i) = z;
        }
        return;
    }
    const float* src; unsigned short* dst; int i, lim;
    if (b < ZB + CB) { src = nodes;   dst = nb; i = ((b - ZB) * 256 + threadIdx.x) * 8;      lim = nfeat; }
    else             { src = weights; dst = wb; i = ((b - ZB - CB) * 256 + threadIdx.x) * 8; lim = nw; }
    if (i < lim) {
        const float4* s = reinterpret_cast<const float4*>(src + i);
        float4 v0 = s[0], v1 = s[1];
        short8 sv;
        sv[0] = f2bf(v0.x); sv[1] = f2bf(v0.y); sv[2] = f2bf(v0.z); sv[3] = f2bf(v0.w);
        sv[4] = f2bf(v1.x); sv[5] = f2bf(v1.y); sv[6] = f2bf(v1.z); sv[7] = f2bf(v1.w);
        *reinterpret_cast<short8*>(dst + i) = sv;
    }
}

// ---------------------------------------------------------------------------
// histogram over full row ids (r*N + dst)
// ---------------------------------------------------------------------------
__global__ __launch_bounds__(256)
void count_kernel(const int* __restrict__ rows, int* __restrict__ cnt, int nnz) {
    int e = blockIdx.x * 256 + threadIdx.x;
    if (e < nnz) atomicAdd(&cnt[rows[e]], 1);
}

// ---------------------------------------------------------------------------
// hierarchical exclusive scan, 1024 elems per 256-thread block (int4).
// ---------------------------------------------------------------------------
__global__ __launch_bounds__(256)
void scan_reduce(const int* __restrict__ cnt, int* __restrict__ bsum, int n) {
    __shared__ int s[256];
    int t = threadIdx.x;
    int i = blockIdx.x * 1024 + t * 4;
    int v = 0;
    if (i + 3 < n) { int4 q = *reinterpret_cast<const int4*>(cnt + i); v = q.x + q.y + q.z + q.w; }
    else { for (int k = 0; k < 4; ++k) if (i + k < n) v += cnt[i + k]; }
    s[t] = v;
    __syncthreads();
    for (int off = 128; off > 0; off >>= 1) {
        if (t < off) s[t] += s[t + off];
        __syncthreads();
    }
    if (t == 0) bsum[blockIdx.x] = s[0];
}

__global__ __launch_bounds__(1024)
void scan_block(int* __restrict__ bsum, int nb) {
    __shared__ int s[1024];
    int t = threadIdx.x;
    s[t] = (t < nb) ? bsum[t] : 0;
    __syncthreads();
    for (int off = 1; off < 1024; off <<= 1) {
        int o = (t >= off) ? s[t - off] : 0;
        __syncthreads();
        s[t] += o;
        __syncthreads();
    }
    if (t < nb) bsum[t] = (t == 0) ? 0 : s[t - 1];
}

__global__ __launch_bounds__(256)
void scan_final(int* __restrict__ cnt, const int* __restrict__ bsum, int n) {
    __shared__ int s[256];
    int t = threadIdx.x;
    int i = blockIdx.x * 1024 + t * 4;
    int4 q = make_int4(0, 0, 0, 0);
    if (i + 3 < n) q = *reinterpret_cast<const int4*>(cnt + i);
    else {
        if (i     < n) q.x = cnt[i];
        if (i + 1 < n) q.y = cnt[i + 1];
        if (i + 2 < n) q.z = cnt[i + 2];
        if (i + 3 < n) q.w = cnt[i + 3];
    }
    int tot = q.x + q.y + q.z + q.w;
    s[t] = tot;
    __syncthreads();
    for (int off = 1; off < 256; off <<= 1) {
        int o = (t >= off) ? s[t - off] : 0;
        __syncthreads();
        s[t] += o;
        __syncthreads();
    }
    int ex = ((t == 0) ? 0 : s[t - 1]) + bsum[blockIdx.x];
    int4 w;
    w.x = ex; w.y = ex + q.x; w.z = w.y + q.y; w.w = w.z + q.z;
    if (i + 3 < n) *reinterpret_cast<int4*>(cnt + i) = w;
    else {
        if (i     < n) cnt[i]     = w.x;
        if (i + 1 < n) cnt[i + 1] = w.y;
        if (i + 2 < n) cnt[i + 2] = w.z;
        if (i + 3 < n) cnt[i + 3] = w.w;
    }
}

// ---------------------------------------------------------------------------
// place: counting-sort pass 2, key = full row id. Record = (val<<32)|col.
// Post-pass: cnt[s] == end(s) == start(s+1).
// ---------------------------------------------------------------------------
__global__ __launch_bounds__(256)
void place_kernel(const int* __restrict__ rows, const int* __restrict__ cols,
                  const float* __restrict__ vals,
                  int* __restrict__ cnt, u64* __restrict__ sorted, int nnz) {
    int e = blockIdx.x * 256 + threadIdx.x;
    if (e >= nnz) return;
    int pos = atomicAdd(&cnt[rows[e]], 1);
    sorted[pos] = ((u64)__float_as_uint(vals[e]) << 32) | (u64)(unsigned int)cols[e];
}

// ---------------------------------------------------------------------------
// gather: one wave per (r,dst) segment. Reads bf16 node rows (256B coalesced,
// 25.6MB cache-resident set), accumulates fp32, writes agg[s] row as packed
// bf16 (256B sequential). Empty segments write zeros (ws is poisoned).
// ---------------------------------------------------------------------------
__global__ __launch_bounds__(256)
void gather_kernel(const u64* __restrict__ sorted, const int* __restrict__ cnt,
                   const unsigned short* __restrict__ nb,
                   unsigned int* __restrict__ agg, int nseg) {
    const int wave = threadIdx.x >> 6;
    const int lane = threadIdx.x & 63;
    const int s = blockIdx.x * 4 + wave;
    if (s >= nseg) return;

    int e         = (s == 0) ? 0 : cnt[s - 1];
    const int end = cnt[s];

    float a0 = 0.f, a1 = 0.f, b0 = 0.f, b1 = 0.f;
    float c0 = 0.f, c1 = 0.f, d0 = 0.f, d1 = 0.f;

#define NROW(q) (reinterpret_cast<const unsigned int*>(nb + (((size_t)(unsigned int)(q)) << 7)))
#define VAL(q)  __uint_as_float((unsigned int)((q) >> 32))
    for (; e + 4 <= end; e += 4) {
        const u64* p = sorted + __builtin_amdgcn_readfirstlane(e);
        u64 q0 = p[0], q1 = p[1], q2 = p[2], q3 = p[3];
        unsigned int x0 = NROW(q0)[lane];
        unsigned int x1 = NROW(q1)[lane];
        unsigned int x2 = NROW(q2)[lane];
        unsigned int x3 = NROW(q3)[lane];
        a0 = fmaf(bflo(x0), VAL(q0), a0); a1 = fmaf(bfhi(x0), VAL(q0), a1);
        b0 = fmaf(bflo(x1), VAL(q1), b0); b1 = fmaf(bfhi(x1), VAL(q1), b1);
        c0 = fmaf(bflo(x2), VAL(q2), c0); c1 = fmaf(bfhi(x2), VAL(q2), c1);
        d0 = fmaf(bflo(x3), VAL(q3), d0); d1 = fmaf(bfhi(x3), VAL(q3), d1);
    }
    for (; e < end; ++e) {
        u64 q0 = sorted[e];
        unsigned int x0 = NROW(q0)[lane];
        a0 = fmaf(bflo(x0), VAL(q0), a0); a1 = fmaf(bfhi(x0), VAL(q0), a1);
    }
#undef NROW
#undef VAL

    float r0 = a0 + b0 + c0 + d0;
    float r1 = a1 + b1 + c1 + d1;
    unsigned int pk = ((unsigned int)f2bf(r1) << 16) | (unsigned int)f2bf(r0);
    agg[((size_t)s << 6) + lane] = pk;     // agg row = 64 uints = 128 bf16
}

// ---------------------------------------------------------------------------
// gemm: out[n,i] = relu( sum_r sum_j agg[r,n,j] * W[r,i,j] )
// 128-node tile / 4 waves, LDS bf16 stride-136. C accumulates across r.
// Epilogue: LDS round-trip (64 rows x stride-132 fp32, fits in wt region),
// coalesced float4 stores. C/D: col = lane&15, row = quad*4 + reg (verified).
// ---------------------------------------------------------------------------
__global__ __launch_bounds__(256, 2)
void gemm_kernel(const unsigned short* __restrict__ agg,
                 const unsigned short* __restrict__ wb,
                 float* __restrict__ out, int N, int R) {
    __shared__ unsigned short nd[128 * LDN];
    __shared__ unsigned short wt[128 * LDN];

    const int t    = threadIdx.x;
    const int n0   = blockIdx.x * 128;
    const int lane = t & 63;
    const int w    = t >> 6;
    const int m    = lane & 15;
    const int quad = lane >> 4;
    const int q8   = quad * 8;
    const int w32  = w * 32;

    f32x4 acc[2][8];
#pragma unroll
    for (int t2 = 0; t2 < 2; ++t2)
#pragma unroll
        for (int j = 0; j < 8; ++j) acc[t2][j] = (f32x4)(0.f);

    for (int r = 0; r < R; ++r) {
        __syncthreads();
        // stage agg[r] tile (guarded rows -> zeros)
        const unsigned short* asrc = agg + ((size_t)r * N + n0) * HFR;
        const unsigned short* wsrc = wb + (size_t)r * HFR * HTO;
#pragma unroll
        for (int it = 0; it < 8; ++it) {
            int id  = t + 256 * it;
            int row = id >> 4;
            int k8  = id & 15;
            short8 sv = (short8)0;
            if (n0 + row < N)
                sv = *reinterpret_cast<const short8*>(asrc + row * HFR + k8 * 8);
            *reinterpret_cast<short8*>(&nd[row * LDN + k8 * 8]) = sv;
            short8 wv = *reinterpret_cast<const short8*>(wsrc + row * HFR + k8 * 8);
            *reinterpret_cast<short8*>(&wt[row * LDN + k8 * 8]) = wv;
        }
        __syncthreads();

#pragma unroll
        for (int kk = 0; kk < HFR; kk += 32) {
            short8 a0 = *reinterpret_cast<const short8*>(&nd[(w32 +      m) * LDN + kk + q8]);
            short8 a1 = *reinterpret_cast<const short8*>(&nd[(w32 + 16 + m) * LDN + kk + q8]);
#pragma unroll
            for (int j = 0; j < 8; ++j) {
                short8 b = *reinterpret_cast<const short8*>(&wt[(j * 16 + m) * LDN + kk + q8]);
                acc[0][j] = __builtin_amdgcn_mfma_f32_16x16x32_bf16(a0, b, acc[0][j], 0, 0, 0);
                acc[1][j] = __builtin_amdgcn_mfma_f32_16x16x32_bf16(a1, b, acc[1][j], 0, 0, 0);
            }
        }
    }

    // ---- epilogue: two 64-row halves through LDS, coalesced f32x4 stores
    float* lf = reinterpret_cast<float*>(wt);   // 64 x 132 floats = 33792B
    for (int h = 0; h < 2; ++h) {
        __syncthreads();
        if ((w >> 1) == h) {
            int lbase = (w & 1) * 32;
#pragma unroll
            for (int t2 = 0; t2 < 2; ++t2)
#pragma unroll
                for (int reg = 0; reg < 4; ++reg) {
                    int lr = lbase + t2 * 16 + quad * 4 + reg;
#pragma unroll
                    for (int j = 0; j < 8; ++j)
                        lf[lr * 132 + m + 16 * j] = acc[t2][j][reg];
                }
        }
        __syncthreads();
#pragma unroll
        for (int it = 0; it < 8; ++it) {
            int id  = t + 256 * it;        // 64 rows x 32 float4
            int row = id >> 5;
            int k4  = id & 31;
            int n = n0 + h * 64 + row;
            if (n < N) {
                float4 v = *reinterpret_cast<const float4*>(&lf[row * 132 + k4 * 4]);
                v.x = fmaxf(v.x, 0.f); v.y = fmaxf(v.y, 0.f);
                v.z = fmaxf(v.z, 0.f); v.w = fmaxf(v.w, 0.f);
                *reinterpret_cast<float4*>(out + (size_t)n * HTO + k4 * 4) = v;
            }
        }
    }
}

// ---------------------------------------------------------------------------
extern "C" void kernel_launch(void* const* d_in, const int* in_sizes, int n_in,
                              void* d_out, int out_size, void* d_ws, size_t ws_size,
                              hipStream_t stream) {
    const float* nodes   = (const float*)d_in[0];   // [N, HFR] fp32
    const int*   indices = (const int*)d_in[1];     // [2, NNZ] int32
    const float* vals    = (const float*)d_in[2];   // [NNZ] fp32
    const float* weights = (const float*)d_in[3];   // [R, HFR, HTO] fp32

    const int N    = in_sizes[0] / HFR;
    const int nnz  = in_sizes[1] / 2;
    const int R    = in_sizes[3] / (HFR * HTO);
    const int nseg = N * R;

    const int* rows = indices;
    const int* cols = indices + nnz;

    // ws layout (217.9 MB, under the 218 MB proven in prior rounds):
    //   agg    : [nseg, 128] bf16   (204.8 MB)
    //   sorted : [nnz] u64          (12.8 MB)
    //   bsum   : [1024] int
    //   wbf16  : [R*128*128] bf16   (0.25 MB)
    char* ws = (char*)d_ws;
    unsigned short* agg = (unsigned short*)ws;
    size_t off = (size_t)nseg * HFR * sizeof(unsigned short);
    u64* sorted = (u64*)(ws + off);
    off += (size_t)nnz * sizeof(u64);
    int* bsum = (int*)(ws + off);
    off += 4096;
    unsigned short* wb = (unsigned short*)(ws + off);

    // d_out doubles as scratch until gemm overwrites every element:
    //   cnt        at d_out[0]       (nseg ints, 3.2 MB)
    //   nodes_bf16 at d_out + 4 MB   (N*128 bf16, 25.6 MB)
    float* out = (float*)d_out;
    int* cnt = (int*)d_out;
    unsigned short* nb = (unsigned short*)((char*)d_out + (4 << 20));

    const int nfeat = N * HFR;           // 12.8M
    const int nw    = R * HFR * HTO;     // 131072
    const int ZB = (nseg + 1023) / 1024;             // zero blocks (int4 x 256)
    const int CB = (nfeat + 2047) / 2048;            // node-convert blocks
    const int WB = (nw + 2047) / 2048;               // weight-convert blocks
    const int EB = (nnz + 255) / 256;                // edge-parallel blocks
    const int NB = (nseg + 1023) / 1024;             // scan blocks (<=1024)

    // 1) zero cnt + convert nodes & weights to bf16
    prep_kernel<<<ZB + CB + WB, 256, 0, stream>>>(nodes, weights, cnt, nb, wb,
                                                  nseg, nfeat, nw, ZB, CB);
    // 2) histogram over full row ids
    count_kernel<<<EB, 256, 0, stream>>>(rows, cnt, nnz);
    // 3) exclusive scan
    scan_reduce<<<NB, 256, 0, stream>>>(cnt, bsum, nseg);
    scan_block<<<1, 1024, 0, stream>>>(bsum, NB);
    scan_final<<<NB, 256, 0, stream>>>(cnt, bsum, nseg);
    // 4) bin edges by row id
    place_kernel<<<EB, 256, 0, stream>>>(rows, cols, vals, cnt, sorted, nnz);
    // 5) segment-sum into agg (bf16)
    gather_kernel<<<(nseg + 3) / 4, 256, 0, stream>>>(sorted, cnt,
                                                      nb, (unsigned int*)agg, nseg);
    // 6) batched GEMM over r with fused relu (overwrites all of d_out)
    gemm_kernel<<<(N + 127) / 128, 256, 0, stream>>>(agg, wb, out, N, R);
}